// Round 7
// baseline (253.803 us; speedup 1.0000x reference)
//
#include <hip/hip_runtime.h>

// RoiAlign / crop_and_resize: B=8, H=64, W=64, C=256, N=512, POOL=7
//
// R11: DIAGNOSTIC ROUND (deliberate). Six structural rewrites (read
// locality x4, store hint, granularity/occupancy) all left the main
// kernel at ~105-108us vs a ~50us component model — and we have never
// seen its counters (every top-5 is the ~124us harness fill; our ~107us
// kernel ranks just below). This round: simplest correct structure (R4
// gather + plain stores) with EVERY OUTPUT STORE ISSUED TWICE (same
// address, same value — idempotent, bit-identical output; asm pointer
// launder between the stores defeats dead-store elimination).
// Purpose: (a) the time delta vs ~114us gives the marginal cost of the
// store path directly (store-bound: +90-105us; healthy: +~30us);
// (b) the kernel now exceeds the 128us fills and surfaces in top-5 with
// FETCH_SIZE / WRITE_SIZE / VALUBusy / Occupancy, localizing the
// invariant ~55us for R12.

#define POOL  7
#define B_    8
#define H_    64
#define W_    64
#define C_    256
#define N_    512
#define CW    (C_ / 4)                  // 64 16B-vectors per spatial pixel
#define ROWS_PER_IMG (N_ * POOL)        // 3584 rows per image
#define ROWS_PER_BLOCK 4                // 4 waves per 256-thread block

typedef float v4f __attribute__((ext_vector_type(4)));

__global__ __launch_bounds__(256) void roialign_kernel(
    const float* __restrict__ fm,      // [B,H,W,C]
    const float* __restrict__ boxes,   // [B,N,4] = x1,y1,x2,y2 normalized
    float* __restrict__ out)           // [B,N,POOL,POOL,C]
{
    // XCD swizzle: image b sticks to XCD b (round-robin block dispatch).
    const int b    = blockIdx.x & 7;
    const int rblk = blockIdx.x >> 3;           // 0..895
    const int wave = threadIdx.x >> 6;          // 0..3
    const int lane = threadIdx.x & 63;
    const int row  = rblk * ROWS_PER_BLOCK + wave;   // 0..3583 (exact)
    const int n    = row / POOL;                // 0..511
    const int py   = row - n * POOL;            // 0..6

    const float* box = boxes + ((b << 9) + n) * 4;
    const float bx1 = box[0], by1 = box[1], bx2 = box[2], by2 = box[3];

    // Match reference expression order exactly:
    //   ys = y1*(H-1) + i * ((y2-y1)*(H-1)/(POOL-1))
    const float sy  = (by2 - by1) * 63.0f / 6.0f;
    const float sx  = (bx2 - bx1) * 63.0f / 6.0f;
    const float yv  = by1 * 63.0f + (float)py * sy;
    const float x0v = bx1 * 63.0f;

    const float yf = floorf(yv);
    const float fy = yv - yf;
    const int   y0 = (int)yf;
    const int   yt = min(max(y0,     0), H_ - 1);
    const int   yb = min(max(y0 + 1, 0), H_ - 1);
    const bool  vy = (yv >= 0.0f) && (yv <= 63.0f);

    const v4f* f4  = (const v4f*)fm;
    const int rowT = (b * (H_ * W_) + yt * W_) * CW + lane;
    const int rowB = (b * (H_ * W_) + yb * W_) * CW + lane;

    v4f* o4 = (v4f*)out + ((((b << 9) + n) * POOL + py) * POOL) * CW + lane;

    #pragma unroll
    for (int px = 0; px < POOL; ++px) {
        const float xv = x0v + (float)px * sx;
        const float xf = floorf(xv);
        const float fx = xv - xf;
        const int   x0 = (int)xf;
        const int   xl = min(max(x0,     0), W_ - 1);
        const int   xr = min(max(x0 + 1, 0), W_ - 1);
        const bool  valid = vy && (xv >= 0.0f) && (xv <= 63.0f);

        const v4f tl = f4[rowT + xl * CW];
        const v4f tr = f4[rowT + xr * CW];
        const v4f bl = f4[rowB + xl * CW];
        const v4f br = f4[rowB + xr * CW];

        const v4f top = tl + (tr - tl) * fx;
        const v4f bot = bl + (br - bl) * fx;
        v4f o = top + (bot - top) * fy;
        if (!valid) o = (v4f)(0.0f);

        // --- double store: measure marginal store-path cost -----------
        v4f* p = o4 + px * CW;
        *p = o;                                  // store #1
        asm volatile("" : "+v"(p));              // launder ptr: no DSE
        *p = o;                                  // store #2 (same value)
    }
}

extern "C" void kernel_launch(void* const* d_in, const int* in_sizes, int n_in,
                              void* d_out, int out_size, void* d_ws, size_t ws_size,
                              hipStream_t stream) {
    const float* fm    = (const float*)d_in[0];   // [8,64,64,256] fp32
    const float* boxes = (const float*)d_in[1];   // [8,512,4] fp32
    float* out         = (float*)d_out;           // [8,512,7,7,256] fp32

    // 4 row-waves per block; 896 blocks per image x 8 images = 7168 blocks.
    const int blocks = (ROWS_PER_IMG / ROWS_PER_BLOCK) * B_;
    roialign_kernel<<<blocks, 256, 0, stream>>>(fm, boxes, out);
}

// Round 8
// 235.013 us; speedup vs baseline: 1.0800x; 1.0800x over previous
//
#include <hip/hip_runtime.h>

// RoiAlign / crop_and_resize: B=8, H=64, W=64, C=256, N=512, POOL=7
//
// R12: de-duplicated staging. R11's double-store diagnostic proved the
// kernel has NEVER been ~110us: a ~130us kernel must top the top-5 and
// did not appear (same in R7). dur_us carries ~186us fixed harness work
// (124us poison fill + ~62us == 2x205MB output verify/copy). Re-read
// ledger with kernel ~= dur-186: R4 gather=60, R8/R9 LDS=50/47,
// R10=45.5 — LDS staging was a -25% WIN mislabeled as null. Floor:
// 205MB writes = 31us + staging ~4 + scan ~= 35-38us.
// This round's single change vs R10: ONE block per (image,bucket)
// (512 blocks, was 1024 with parity split) -> each 64KiB fm row staged
// once instead of twice (staging traffic 134->67MB), scan work halved.
// Same 72.7KiB LDS -> still 2 blocks/CU, 16 waves/CU.
// Keep: fused bucketing (no prologue dispatch), tl/tr from LDS, bl/br
// from L2/L3, plain writeback stores, image->XCD pin, exact reference
// x-path math, y via bucket identity (yt==bk, fy=yv-bk: continuous at
// boundaries, 1-ulp build/process divergence safe).

#define POOL  7
#define B_    8
#define H_    64
#define W_    64
#define C_    256
#define N_    512
#define CW    (C_ / 4)                   // 64 16B-quads per spatial pixel
#define ROWQ  (W_ * CW)                  // 4096 quads per fm row (64 KiB)
#define MAXI  3584                       // worst-case items in one bucket

typedef float v4f __attribute__((ext_vector_type(4)));
typedef unsigned short u16;

__global__ __launch_bounds__(512) void roialign_kernel(
    const float* __restrict__ fm,      // [B,H,W,C]
    const float* __restrict__ boxes,   // [B,N,4] x1,y1,x2,y2 normalized
    float* __restrict__ out)           // [B,N,POOL,POOL,C]
{
    extern __shared__ v4f lds[];           // [ROWQ] staged row bk (64 KiB)
    u16* list = (u16*)(lds + ROWQ);        // [MAXI] item codes (7 KiB)
    __shared__ int cnt;

    const int b    = blockIdx.x & 7;       // image -> XCD pin
    const int bk   = blockIdx.x >> 3;      // fm row bucket 0..63
    const int tid  = threadIdx.x;          // 0..511
    const int wave = tid >> 6;             // 0..7
    const int lane = tid & 63;             // channel-quad
    const v4f* f4  = (const v4f*)fm;

    if (tid == 0) cnt = 0;
    __syncthreads();

    // ---- stage row bk (full channels, 64 KiB), coalesced ---------------
    {
        const int base0 = (b * H_ + bk) * ROWQ;
        #pragma unroll
        for (int k = 0; k < 8; ++k)
            lds[k * 512 + tid] = f4[base0 + k * 512 + tid];
    }

    // ---- fused bucketing: thread n scans its box's 7 samples -----------
    {
        const int n = tid;                 // 0..511
        const float by1 = boxes[(((b << 9) + n) << 2) + 1];
        const float by2 = boxes[(((b << 9) + n) << 2) + 3];
        const float sy  = (by2 - by1) * 63.0f / 6.0f;
        #pragma unroll
        for (int py = 0; py < POOL; ++py) {
            const float yv = by1 * 63.0f + (float)py * sy;
            const int y0  = (int)floorf(yv);
            const int bkk = min(max(y0, 0), H_ - 1);
            if (bkk == bk) {
                const int pos = atomicAdd(&cnt, 1);
                list[pos] = (u16)((n << 3) | py);
            }
        }
    }
    __syncthreads();

    const int nItems   = cnt;
    const int yb       = min(bk + 1, H_ - 1);
    const int rowBbase = (b * (H_ * W_) + yb * W_) * CW + lane;
    const float yfB    = (float)bk;

    for (int it = wave; it < nItems; it += 8) {
        const int code = __builtin_amdgcn_readfirstlane((int)list[it]);
        const int n  = code >> 3;
        const int py = code & 7;

        const float* box = boxes + (((b << 9) + n) << 2);
        const float bx1 = box[0], by1 = box[1], bx2 = box[2], by2 = box[3];

        // Match reference expression order exactly (x path), y via bucket:
        const float sy  = (by2 - by1) * 63.0f / 6.0f;
        const float sx  = (bx2 - bx1) * 63.0f / 6.0f;
        const float yv  = by1 * 63.0f + (float)py * sy;
        const float x0v = bx1 * 63.0f;

        // yt == bk by bucketing; fy relative to bk is continuous across
        // any 1-ulp build/process divergence at integer boundaries.
        const float fy = yv - yfB;
        const bool  vy = (yv >= 0.0f) && (yv <= 63.0f);

        v4f* o4 = (v4f*)out + ((((b << 9) + n) * POOL + py) * POOL) * CW + lane;

        #pragma unroll
        for (int px = 0; px < POOL; ++px) {
            const float xv = x0v + (float)px * sx;
            const float xf = floorf(xv);
            const float fx = xv - xf;
            const int   x0 = (int)xf;
            const int   xl = min(max(x0,     0), W_ - 1);
            const int   xr = min(max(x0 + 1, 0), W_ - 1);
            const bool  valid = vy && (xv >= 0.0f) && (xv <= 63.0f);

            const v4f tl = lds[xl * CW + lane];          // row bk from LDS
            const v4f tr = lds[xr * CW + lane];
            const v4f bl = f4[rowBbase + xl * CW];       // row bk+1 from L2/L3
            const v4f br = f4[rowBbase + xr * CW];

            const v4f top = tl + (tr - tl) * fx;
            const v4f bot = bl + (br - bl) * fx;
            v4f o = top + (bot - top) * fy;
            if (!valid) o = (v4f)(0.0f);

            o4[px * CW] = o;               // plain store: completes at L2
        }
    }
}

extern "C" void kernel_launch(void* const* d_in, const int* in_sizes, int n_in,
                              void* d_out, int out_size, void* d_ws, size_t ws_size,
                              hipStream_t stream) {
    const float* fm    = (const float*)d_in[0];   // [8,64,64,256] fp32
    const float* boxes = (const float*)d_in[1];   // [8,512,4] fp32
    float* out         = (float*)d_out;           // [8,512,7,7,256] fp32

    // 1 block per (image, bucket): 64 buckets x 8 images = 512 blocks.
    // Dynamic LDS: 64 KiB row + 7 KiB list = 72704 B -> 2 blocks/CU.
    const size_t ldsB = ROWQ * sizeof(v4f) + MAXI * sizeof(u16);
    roialign_kernel<<<H_ * B_, 512, ldsB, stream>>>(fm, boxes, out);
}